// Round 15
// baseline (142.297 us; speedup 1.0000x reference)
//
#include <hip/hip_runtime.h>
#include <cfloat>

#define B_  16
#define N_  500   // INPUT_SIZE
#define NP  512   // padded N
#define S_  128   // SENTENCE_SIZE
#define D_  512
#define FO  128   // ori head dim
#define FI  64    // in/out head dim

typedef unsigned short u16;
typedef __attribute__((ext_vector_type(8))) short bf8;
typedef __attribute__((ext_vector_type(4))) float f4;

#define MFMA(a,b,c) __builtin_amdgcn_mfma_f32_16x16x32_bf16((a),(b),(c),0,0,0)

__device__ __forceinline__ u16 f2b(float x){
    union{float f;unsigned u;} v; v.f=x;
    unsigned r = v.u + 0x7fffu + ((v.u>>16)&1u);
    return (u16)(r>>16);
}
__device__ __forceinline__ float b2f(u16 x){
    union{unsigned u;float f;} v; v.u=((unsigned)x)<<16; return v.f;
}
__device__ __forceinline__ bf8 ldb8(const u16* p){ return *(const bf8*)p; }

__device__ __forceinline__ void gl2lds16(const u16* g, u16* lds){
    __builtin_amdgcn_global_load_lds(
        (const __attribute__((address_space(1))) unsigned int*)g,
        (__attribute__((address_space(3))) unsigned int*)lds, 16, 0, 0);
}

// =====================================================================
// prep_fused: code/weight transposes + sent prep + pad zeroing, 1 launch.
// =====================================================================
struct PWAll { const float* W[8]; u16* WT[8]; };
__global__ __launch_bounds__(256) void prep_fused(const float* __restrict__ code,
                                                  u16* __restrict__ codeB,
                                                  u16* __restrict__ codeT,
                                                  PWAll a,
                                                  const float* __restrict__ sent,
                                                  u16* __restrict__ sentB,
                                                  float* __restrict__ inc,
                                                  u16* a0, u16* a1, u16* a2, u16* a3)
{
    __shared__ float T[64][65];
    const int t = threadIdx.x;
    const int x = blockIdx.x;
    if (x < 1024){
        const int b  = x >> 6;
        const int m0 = ((x >> 3) & 7) * 64;
        const int d0 = (x & 7) * 64;
        #pragma unroll
        for (int i=0;i<16;++i){
            int idx = t + i*256; int rr = idx>>6, cc = idx&63;
            int m = m0+rr;
            T[rr][cc] = (m < N_) ? code[((size_t)b*N_+m)*D_ + d0+cc] : 0.f;
        }
        __syncthreads();
        #pragma unroll
        for (int i=0;i<16;++i){
            int idx=t+i*256; int rr=idx>>6, cc=idx&63; int m=m0+rr;
            if (m<N_) codeB[((size_t)b*N_+m)*D_ + d0+cc] = f2b(T[rr][cc]);
        }
        #pragma unroll
        for (int i=0;i<16;++i){
            int idx=t+i*256; int dd=idx>>6, mm=idx&63;
            codeT[((size_t)b*D_ + d0+dd)*NP + m0+mm] = f2b(T[mm][dd]);
        }
    } else if (x < 1344){
        const int v    = x - 1024;
        const int h    = v / 80;
        const int rem  = v - h*80;
        const int slot = rem >> 3;
        const int d0   = (rem & 7) * 64;
        const int widx = slot<4 ? (slot>>1) : slot-2;
        const int ftile= slot<4 ? (slot&1)  : 0;
        const int F    = slot<4 ? 128 : 64;
        const float* W = a.W[widx];
        u16* WT        = a.WT[widx];
        const int f0 = ftile*64;
        #pragma unroll
        for (int i=0;i<16;++i){
            int idx=t+i*256; int rr=idx>>6, cc=idx&63;
            T[rr][cc] = W[((size_t)h*D_ + d0+rr)*F + f0+cc];
        }
        __syncthreads();
        #pragma unroll
        for (int i=0;i<16;++i){
            int idx=t+i*256; int ff=idx>>6, dd=idx&63;
            WT[((size_t)h*F + f0+ff)*D_ + d0+dd] = f2b(T[dd][ff]);
        }
    } else if (x < 2368){
        const int y  = x - 1344;
        const int b  = y >> 6;
        const int s  = (y & 63)*2 + (t >> 7);
        const int tl = t & 127;
        const float* row = sent + ((size_t)b*S_+s)*N_;
        float4 v = make_float4(0.f,0.f,0.f,0.f);
        const int n = tl*4;
        if (n < N_) v = *(const float4*)(row+n);
        float sum = v.x+v.y+v.z+v.w;
        ushort4 o; o.x=f2b(v.x); o.y=f2b(v.y); o.z=f2b(v.z); o.w=f2b(v.w);
        *(ushort4*)&sentB[((size_t)b*S_+s)*NP + n] = o;
        #pragma unroll
        for (int off=32; off; off>>=1) sum += __shfl_down(sum, off);
        __shared__ float ls[4];
        if ((t&63)==0) ls[t>>6]=sum;
        __syncthreads();
        if (tl==0) inc[b*S_+s] = ls[(t>>7)*2] + ls[(t>>7)*2+1];
    } else {
        const int u  = x - 2368;
        u16* arr4[4] = {a0,a1,a2,a3};
        u16* base = arr4[u>>6] + (size_t)(u&63)*FI*NP;
        for (int idx=t; idx<FI*12; idx+=256){
            int f = idx/12, n = N_ + idx%12;
            base[(size_t)f*NP + n] = 0;
        }
    }
}

// =====================================================================
// proj_body: 128x128 tile, 4 waves, 3-buffer depth-2 counted-vmcnt modulo
// pipeline, source-chunk XOR swizzle, LDS-staged coalesced stores.
// =====================================================================
struct GemmOut { const float* bias[8]; u16* dst[8]; };
union ProjLDS {
    u16 ab[6][4096];   // A0,A1,A2,B0,B1,B2 (each 128 rows x 32 k, linear)
    u16 ot[16896];     // 128x132 output staging tile
};

#define PG_WAIT(NN) asm volatile("s_waitcnt vmcnt(" #NN ")" ::: "memory")
#define PG_FENCE()  asm volatile("" ::: "memory")

#define PG_STAGE(ai, bi, kk) { \
    gl2lds16(codeB + (size_t)(r0 + w*32      + srow)*D_ + (kk) + cgs, &Lp->ab[ai][(w*32)*32]);     \
    gl2lds16(WallT + (size_t)(c0 + w*32      + srow)*D_ + (kk) + cgs, &Lp->ab[bi][(w*32)*32]);     \
    gl2lds16(codeB + (size_t)(r0 + w*32 + 16 + srow)*D_ + (kk) + cgs, &Lp->ab[ai][(w*32+16)*32]);  \
    gl2lds16(WallT + (size_t)(c0 + w*32 + 16 + srow)*D_ + (kk) + cgs, &Lp->ab[bi][(w*32+16)*32]);  \
}

#define PG_COMPUTE(ai, bi) { \
    bf8 af[4], bfr[4]; \
    _Pragma("unroll") \
    for (int i=0;i<4;++i){ \
        af[i]  = *(const bf8*)&Lp->ab[ai][(wr + i*16 + lane16)*32 + kread]; \
        bfr[i] = *(const bf8*)&Lp->ab[bi][(wc + i*16 + lane16)*32 + kread]; \
    } \
    _Pragma("unroll") \
    for (int i=0;i<4;++i) \
        _Pragma("unroll") \
        for (int j=0;j<4;++j) \
            acc[i][j] = MFMA(af[i], bfr[j], acc[i][j]); \
}

#define PG_STEP(WN, ai, bi, jn) { \
    PG_WAIT(WN); \
    __builtin_amdgcn_s_barrier(); \
    PG_FENCE(); \
    __builtin_amdgcn_s_setprio(1); \
    PG_COMPUTE(ai, bi); \
    __builtin_amdgcn_s_setprio(0); \
    __builtin_amdgcn_s_barrier(); \
    PG_FENCE(); \
    if ((jn) < 16) PG_STAGE(ai, bi, (jn)*32); \
}

static __device__ __forceinline__ void proj_body(const u16* __restrict__ codeB,
                                                 const u16* __restrict__ WallT,
                                                 const GemmOut& go,
                                                 ProjLDS* Lp,
                                                 int bid, int t, int NCT, int CT0)
{
    const int w = t>>6, l = t&63, lane16 = l&15, lq = l>>4;
    const int xcd = bid & 7;
    const int g   = bid >> 3;
    const int rt  = xcd*8 + g/NCT;       // 0..63
    const int ct  = CT0 + (g - (g/NCT)*NCT);
    const int r0 = rt*128;
    const int c0 = ct*128;
    const int wr = (w>>1)*64, wc = (w&1)*64;
    const int srow = l>>2;
    const int cgs  = ((l&3) ^ ((srow>>1)&3))*8;
    const int kread= (lq ^ ((lane16>>1)&3))*8;

    f4 acc[4][4] = {};

    PG_STAGE(0,3, 0);
    PG_STAGE(1,4, 32);
    PG_STAGE(2,5, 64);

    PG_STEP(8, 0,3, 3);
    PG_STEP(8, 1,4, 4);
    PG_STEP(8, 2,5, 5);
    PG_STEP(8, 0,3, 6);
    PG_STEP(8, 1,4, 7);
    PG_STEP(8, 2,5, 8);
    PG_STEP(8, 0,3, 9);
    PG_STEP(8, 1,4, 10);
    PG_STEP(8, 2,5, 11);
    PG_STEP(8, 0,3, 12);
    PG_STEP(8, 1,4, 13);
    PG_STEP(8, 2,5, 14);
    PG_STEP(8, 0,3, 15);
    PG_STEP(8, 1,4, 16);
    PG_STEP(4, 2,5, 17);
    PG_STEP(0, 0,3, 18);

    const int ri = (ct<4) ? 0 : (ct<8) ? 1 : 2 + ((ct-8)>>1);
    const bool tr = (ri==2)||(ri==4)||(ri==5)||(ri==7);

    __syncthreads();

    #pragma unroll
    for (int j=0;j<4;++j){
        const int c = c0 + wc + j*16 + lane16;
        const int idx = (c < 1024) ? (c & 511) : ((c-1024) & 255);
        const float bv = go.bias[ri][idx];
        if (tr){
            #pragma unroll
            for (int i=0;i<4;++i){
                ushort4 o4;
                float x0=acc[i][j][0]+bv, x1=acc[i][j][1]+bv, x2=acc[i][j][2]+bv, x3=acc[i][j][3]+bv;
                o4.x=f2b(x0>0.f?x0:0.f); o4.y=f2b(x1>0.f?x1:0.f);
                o4.z=f2b(x2>0.f?x2:0.f); o4.w=f2b(x3>0.f?x3:0.f);
                *(ushort4*)&Lp->ot[(wc+j*16+lane16)*132 + wr+i*16+lq*4] = o4;
            }
        } else {
            #pragma unroll
            for (int i=0;i<4;++i)
                #pragma unroll
                for (int reg=0;reg<4;++reg){
                    float x = acc[i][j][reg] + bv;
                    Lp->ot[(wr+i*16+lq*4+reg)*132 + wc+j*16+lane16] = f2b(x>0.f?x:0.f);
                }
        }
    }
    __syncthreads();

    if (tr){
        const int c  = t>>1;
        const int cg = c0 + c;
        const int u  = cg - 1024;
        const int hfv = u & 255, h = hfv>>6, f2 = hfv & 63;
        u16* dbase = go.dst[ri];
        const int half = t & 1;
        #pragma unroll
        for (int k2=0;k2<16;++k2){
            const int r  = half*64 + k2*4;
            const int rb = r0 + r;
            if (rb < 8000){
                const int b = rb/500, n = rb - b*500;
                *(ushort4*)&dbase[((size_t)(b*4+h)*FI + f2)*NP + n] =
                    *(const ushort4*)&Lp->ot[c*132 + r];
            }
        }
    } else {
        const int r  = t>>1;
        const int rb = r0 + r;
        if (rb < 8000){
            const int b = rb/500, n = rb - b*500;
            const int half = t & 1;
            const int cg0 = c0 + half*64;
            int h, f2base, F2;
            if (cg0 < 1024){ const int hf0 = cg0 & 511; h = hf0>>7; f2base = hf0 & 127; F2 = 128; }
            else           { const int hf0 = (cg0-1024) & 255; h = hf0>>6; f2base = hf0 & 63; F2 = 64; }
            u16* dstp = go.dst[ri] + ((size_t)(b*4+h)*N_ + n)*F2 + f2base;
            #pragma unroll
            for (int k2=0;k2<16;++k2)
                *(ushort4*)&dstp[k2*4] = *(const ushort4*)&Lp->ot[r*132 + half*64 + k2*4];
        }
    }
}

// =====================================================================
// proj_a: ori col-tiles (ct 0..7). grid 512 (64 rt x 8 ct), block 256.
// =====================================================================
__global__ __launch_bounds__(256) void proj_a(const u16* __restrict__ codeB,
                                              const u16* __restrict__ WallT,
                                              GemmOut go)
{
    __shared__ alignas(16) ProjLDS L;
    proj_body(codeB, WallT, go, &L, blockIdx.x, threadIdx.x, 8, 0);
}

// =====================================================================
// projfi_ms: FI col-tiles (768 blocks, ct 8..19) + ms_mfma (512 blocks).
// =====================================================================
struct MsLDS  { u16 Qs[64][136]; u16 Ks[128][136]; };
union PMLDS   { ProjLDS p; MsLDS ms; };

__global__ __launch_bounds__(256) void projfi_ms(const u16* __restrict__ codeB,
                                                 const u16* __restrict__ WallT,
                                                 GemmOut go,
                                                 const u16* __restrict__ q,
                                                 const u16* __restrict__ k,
                                                 u16* __restrict__ maxscT)
{
    __shared__ alignas(16) PMLDS L;
    const int t=threadIdx.x, x=blockIdx.x;
    if (x < 768){
        proj_body(codeB, WallT, go, &L.p, x, t, 12, 8);
        return;
    }
    // ---------------- ms part ----------------
    const int idx = x - 768;
    const int w=t>>6, l=t&63, lane16=l&15, lq=l>>4;
    const int b=idx&15, n0=((idx>>4)&7)*64, m0=(idx>>7)*128;
    const int wr=(w>>1)*32, wc=(w&1)*64;

    f4 best[2][4];
    #pragma unroll
    for(int rt=0;rt<2;++rt)
        #pragma unroll
        for(int ct=0;ct<4;++ct)
            #pragma unroll
            for(int i=0;i<4;++i) best[rt][ct][i] = -FLT_MAX;

    for (int h=0;h<4;++h){
        const u16* qh = q + (size_t)(b*4+h)*N_*FO;
        const u16* kh = k + (size_t)(b*4+h)*N_*FO;
        #pragma unroll
        for (int i=0;i<4;++i){
            const int e=t+i*256, row=e>>4, kc=(e&15)*8;
            int n=n0+row; if(n>N_-1)n=N_-1;
            *(bf8*)&L.ms.Qs[row][kc] = ldb8(qh + (size_t)n*FO + kc);
        }
        #pragma unroll
        for (int i=0;i<8;++i){
            const int e=t+i*256, row=e>>4, kc=(e&15)*8;
            int m=m0+row; if(m>N_-1)m=N_-1;
            *(bf8*)&L.ms.Ks[row][kc] = ldb8(kh + (size_t)m*FO + kc);
        }
        __syncthreads();
        f4 acc[2][4]={};
        #pragma unroll
        for (int kk=0;kk<FO;kk+=32){
            bf8 a0=*(const bf8*)&L.ms.Qs[wr+lane16][kk+lq*8];
            bf8 a1=*(const bf8*)&L.ms.Qs[wr+16+lane16][kk+lq*8];
            #pragma unroll
            for(int ct=0;ct<4;++ct){
                bf8 bb=*(const bf8*)&L.ms.Ks[wc+ct*16+lane16][kk+lq*8];
                acc[0][ct]=MFMA(a0,bb,acc[0][ct]);
                acc[1][ct]=MFMA(a1,bb,acc[1][ct]);
            }
        }
        #pragma unroll
        for(int rt=0;rt<2;++rt)
            #pragma unroll
            for(int ct=0;ct<4;++ct)
                #pragma unroll
                for(int i=0;i<4;++i) best[rt][ct][i] = fmaxf(best[rt][ct][i], acc[rt][ct][i]);
        __syncthreads();
    }
    #pragma unroll
    for(int rt=0;rt<2;++rt)
        #pragma unroll
        for(int ct=0;ct<4;++ct){
            const int m  = m0+wc+ct*16+lane16;
            const int nb = n0+wr+rt*16+lq*4;
            ushort4 o; o.x=f2b(best[rt][ct][0]); o.y=f2b(best[rt][ct][1]);
            o.z=f2b(best[rt][ct][2]); o.w=f2b(best[rt][ct][3]);
            *(ushort4*)&maxscT[((size_t)b*NP+m)*NP + nb] = o;
        }
}

// =====================================================================
// attn_saoo: attn (512 blocks) + saoo@4-waves (128 blocks), one launch.
// attn idx: bh=idx&63, s0=((idx>>6)&3)*32, br=idx>>8
// saoo idx: b=idx&15, s0=(idx>>4)*16  (xcd = b&7 -> slice L2-local)
// qs partials stored bf16 -> LDS 41.4KB -> 3 blocks/CU. NO setprio (R14
// regression: boosted region contained VMEM loads -> starved co-residents).
// =====================================================================
struct AttnArgs { const u16* qT[2]; const u16* kp[2]; const u16* vT[2]; };
struct AtLDS  { u16 red[4][32][72]; u16 qsS[32][72]; u16 Pw[4][32][72]; };
union ASLDS   { AtLDS at; u16 sAmS[16][520]; };

__global__ __launch_bounds__(256) void attn_saoo(AttnArgs a,
                                                 const u16* __restrict__ sentB,
                                                 const float* __restrict__ inc,
                                                 const u16* __restrict__ maxscT,
                                                 const u16* __restrict__ codeT,
                                                 float* __restrict__ out)
{
    __shared__ alignas(16) ASLDS L;
    const int t=threadIdx.x, w=t>>6, l=t&63, lane16=l&15, lq=l>>4;
    const int x = blockIdx.x;

    if (x < 512){
        // ---------------- attn part ----------------
        const int idx=x, bh=idx&63, b=bh>>2, h=bh&3, s0=((idx>>6)&3)*32, br=idx>>8;
        const u16* qT = a.qT[br];
        const u16* kp = a.kp[br];
        const u16* vT = a.vT[br];

        { // phase 1: qs partial, k-range [w*128, w*128+128), bf16 partials
            const u16 *ap[2], *bp[4];
            #pragma unroll
            for(int rt=0;rt<2;++rt) ap[rt] = sentB + ((size_t)b*S_ + s0+rt*16+lane16)*NP + w*128 + lq*8;
            #pragma unroll
            for(int ct=0;ct<4;++ct) bp[ct] = qT + ((size_t)bh*FI + ct*16+lane16)*NP + w*128 + lq*8;
            f4 acc[2][4] = {};
            #pragma unroll
            for (int k0=0;k0<128;k0+=32){
                bf8 a0=ldb8(ap[0]+k0), a1=ldb8(ap[1]+k0);
                #pragma unroll
                for(int ct=0;ct<4;++ct){
                    bf8 bb=ldb8(bp[ct]+k0);
                    acc[0][ct]=MFMA(a0,bb,acc[0][ct]);
                    acc[1][ct]=MFMA(a1,bb,acc[1][ct]);
                }
            }
            #pragma unroll
            for(int rt=0;rt<2;++rt)
                #pragma unroll
                for(int ct=0;ct<4;++ct)
                    #pragma unroll
                    for(int reg=0;reg<4;++reg)
                        L.at.red[w][rt*16+lq*4+reg][ct*16+lane16] = f2b(acc[rt][ct][reg]);
        }
        __syncthreads();
        {
            const int s=t>>3, f0=(t&7)*8;
            #pragma unroll
            for (int j=0;j<8;++j){
                float v = b2f(L.at.red[0][s][f0+j])+b2f(L.at.red[1][s][f0+j])
                        + b2f(L.at.red[2][s][f0+j])+b2f(L.at.red[3][s][f0+j]);
                L.at.qsS[s][f0+j] = f2b(v);
            }
        }
        __syncthreads();

        f4 accO[2][4] = {};
        #pragma unroll
        for (int c=0;c<2;++c){
            const int m0 = w*64 + c*256;
            f4 p[2][4] = {};
            const u16* bp[4];
            #pragma unroll
            for(int ct=0;ct<4;++ct){
                int m=m0+ct*16+lane16; if(m>N_-1)m=N_-1;
                bp[ct] = kp + ((size_t)bh*N_+m)*FI + lq*8;
            }
            #pragma unroll
            for (int kk=0; kk<FI; kk+=32){
                bf8 a0 = *(const bf8*)&L.at.qsS[lane16][kk+lq*8];
                bf8 a1 = *(const bf8*)&L.at.qsS[16+lane16][kk+lq*8];
                #pragma unroll
                for(int ct=0;ct<4;++ct){
                    bf8 bb=ldb8(bp[ct]+kk);
                    p[0][ct]=MFMA(a0,bb,p[0][ct]);
                    p[1][ct]=MFMA(a1,bb,p[1][ct]);
                }
            }
            #pragma unroll
            for(int rt=0;rt<2;++rt)
                #pragma unroll
                for(int ct=0;ct<4;++ct){
                    const int m = m0+ct*16+lane16;
                    #pragma unroll
                    for(int reg=0;reg<4;++reg){
                        const int s = s0+rt*16+lq*4+reg;
                        const float sv = b2f(sentB[((size_t)b*S_+s)*NP+m]);
                        const float wgt = br ? ((m<N_)? sv-1.f : 0.f) : sv;
                        L.at.Pw[w][rt*16+lq*4+reg][ct*16+lane16] = f2b(p[rt][ct][reg]*wgt);
                    }
                }
            #pragma unroll
            for (int kk2=0; kk2<64; kk2+=32){
                bf8 a2[2];
                #pragma unroll
                for(int rt=0;rt<2;++rt) a2[rt] = *(const bf8*)&L.at.Pw[w][rt*16+lane16][kk2+lq*8];
                #pragma unroll
                for(int ct=0;ct<4;++ct){
                    bf8 vv = ldb8(vT + ((size_t)bh*FI + ct*16+lane16)*NP + m0+kk2+lq*8);
                    accO[0][ct]=MFMA(a2[0],vv,accO[0][ct]);
                    accO[1][ct]=MFMA(a2[1],vv,accO[1][ct]);
                }
            }
        }
        __syncthreads();   // red reuse below
        #pragma unroll
        for(int rt=0;rt<2;++rt)
            #pragma unroll
            for(int ct=0;ct<4;++ct)
                #pragma unroll
                for(int reg=0;reg<4;++reg)
                    L.at.red[w][rt*16+lq*4+reg][ct*16+lane16] = f2b(accO[rt][ct][reg]);
        __syncthreads();
        {
            const int s=t>>3, f0=(t&7)*8;
            float fac = 1.f;
            if (br){ const float ic = inc[b*S_+s0+s]; fac = ic/(500.f-ic); }
            const size_t o = ((size_t)b*S_+s0+s)*1024 + (br?768:512) + h*FI + f0;
            #pragma unroll
            for (int j=0;j<8;++j){
                float v = b2f(L.at.red[0][s][f0+j])+b2f(L.at.red[1][s][f0+j])
                        + b2f(L.at.red[2][s][f0+j])+b2f(L.at.red[3][s][f0+j]);
                out[o+j] = v*fac;
            }
        }
    } else {
        // ---------------- saoo part (4 waves, 2 chunks/wave/phase) ----------------
        const int idx = x - 512;
        const int b = idx&15, s0 = (idx>>4)*16;   // xcd = b&7: same-b s-tiles colocated

        #pragma unroll
        for (int c=0;c<2;++c){ // phase 1: m-chunks w and w+4
            const int m0 = (w + c*4)*64;
            const u16* ap = sentB + ((size_t)b*S_ + s0+lane16)*NP + lq*8;
            const u16* bp[4];
            #pragma unroll
            for(int ct=0;ct<4;++ct) bp[ct] = maxscT + ((size_t)b*NP + m0+ct*16+lane16)*NP + lq*8;
            f4 acc[4] = {};
            for (int k0=0;k0<NP;k0+=32){
                bf8 av=ldb8(ap+k0);
                #pragma unroll
                for(int ct=0;ct<4;++ct) acc[ct]=MFMA(av, ldb8(bp[ct]+k0), acc[ct]);
            }
            #pragma unroll
            for(int ct=0;ct<4;++ct){
                const int m = m0+ct*16+lane16;
                #pragma unroll
                for(int reg=0;reg<4;++reg){
                    const int s = s0+lq*4+reg;
                    const float sv = b2f(sentB[((size_t)b*S_+s)*NP+m]);
                    L.sAmS[lq*4+reg][m] = (sv != 0.f) ? f2b(acc[ct][reg]*sv) : (u16)0;
                }
            }
        }
        __syncthreads();
        #pragma unroll
        for (int c=0;c<2;++c){ // phase 2: d-chunks w and w+4
            const int d0 = (w + c*4)*64;
            const u16* bp[4];
            #pragma unroll
            for(int ct=0;ct<4;++ct) bp[ct] = codeT + ((size_t)b*D_ + d0+ct*16+lane16)*NP + lq*8;
            f4 acc[4] = {};
            for (int k0=0;k0<NP;k0+=32){
                bf8 av = *(const bf8*)&L.sAmS[lane16][k0+lq*8];
                #pragma unroll
                for(int ct=0;ct<4;++ct) acc[ct]=MFMA(av, ldb8(bp[ct]+k0), acc[ct]);
            }
            #pragma unroll
            for(int ct=0;ct<4;++ct){
                const int d = d0+ct*16+lane16;
                #pragma unroll
                for(int reg=0;reg<4;++reg){
                    const int s = s0+lq*4+reg;
                    out[((size_t)b*S_+s)*1024 + d] = acc[ct][reg];
                }
            }
        }
    }
}

// =====================================================================
extern "C" void kernel_launch(void* const* d_in, const int* in_sizes, int n_in,
                              void* d_out, int out_size, void* d_ws, size_t ws_size,
                              hipStream_t stream)
{
    const float* code   = (const float*)d_in[0];
    const float* sent   = (const float*)d_in[1];
    const float* Wq_ori = (const float*)d_in[2];
    const float* bq_ori = (const float*)d_in[3];
    const float* Wk_ori = (const float*)d_in[4];
    const float* bk_ori = (const float*)d_in[5];
    const float* Wq_in  = (const float*)d_in[6];
    const float* bq_in  = (const float*)d_in[7];
    const float* Wk_in  = (const float*)d_in[8];
    const float* bk_in  = (const float*)d_in[9];
    const float* Wv_in  = (const float*)d_in[10];
    const float* bv_in  = (const float*)d_in[11];
    const float* Wq_out = (const float*)d_in[12];
    const float* bq_out = (const float*)d_in[13];
    const float* Wk_out = (const float*)d_in[14];
    const float* bk_out = (const float*)d_in[15];
    const float* Wv_out = (const float*)d_in[16];
    const float* bv_out = (const float*)d_in[17];
    float* out = (float*)d_out;

    // fully disjoint workspace (~71 MB; ws is ~268 MB)
    char* w = (char*)d_ws;
    u16*   codeB  = (u16*)(w);                  // 8192*512*2 = 8,388,608 B
    u16*   WallT  = (u16*)(w + 8388608);        // 2560*512*2 = 2,621,440 B
    u16*   WTqo   = WallT;
    u16*   WTko   = WallT +  262144;
    u16*   WTqi   = WallT +  524288;
    u16*   WTki   = WallT +  655360;
    u16*   WTvi   = WallT +  786432;
    u16*   WTqu   = WallT +  917504;
    u16*   WTku   = WallT + 1048576;
    u16*   WTvu   = WallT + 1179648;
    u16*   sentB  = (u16*)(w + 11010048);       // 2,097,152
    float* incp   = (float*)(w + 13107200);     // 8,192
    u16* q_ori  = (u16*)(w + 13115392);         // 8,192,000
    u16* k_ori  = (u16*)(w + 21307392);         // 8,192,000
    u16* maxscT = (u16*)(w + 29499392);         // 8,388,608
    u16* codeT  = (u16*)(w + 37888000);         // 8,388,608
    u16* k_in   = (u16*)(w + 46276608);         // 4,096,000
    u16* k_out  = (u16*)(w + 50372608);         // 4,096,000
    u16* qT_in  = (u16*)(w + 54468608);         // 4,194,304
    u16* qT_out = (u16*)(w + 58662912);
    u16* vT_in  = (u16*)(w + 62857216);
    u16* vT_out = (u16*)(w + 67051520);         // ends 71,245,824

    // ---- prep (1 launch) ----
    PWAll pw;
    pw.W[0]=Wq_ori; pw.W[1]=Wk_ori; pw.W[2]=Wq_in; pw.W[3]=Wk_in;
    pw.W[4]=Wv_in;  pw.W[5]=Wq_out; pw.W[6]=Wk_out; pw.W[7]=Wv_out;
    pw.WT[0]=WTqo; pw.WT[1]=WTko; pw.WT[2]=WTqi; pw.WT[3]=WTki;
    pw.WT[4]=WTvi; pw.WT[5]=WTqu; pw.WT[6]=WTku; pw.WT[7]=WTvu;
    prep_fused<<<dim3(2624), 256, 0, stream>>>(code, codeB, codeT, pw,
                                               sent, sentB, incp,
                                               qT_in, qT_out, vT_in, vT_out);

    GemmOut go;
    go.bias[0]=bq_ori; go.bias[1]=bk_ori; go.bias[2]=bq_in; go.bias[3]=bk_in;
    go.bias[4]=bv_in;  go.bias[5]=bq_out; go.bias[6]=bk_out; go.bias[7]=bv_out;
    go.dst[0]=q_ori; go.dst[1]=k_ori; go.dst[2]=qT_in; go.dst[3]=k_in;
    go.dst[4]=vT_in; go.dst[5]=qT_out; go.dst[6]=k_out; go.dst[7]=vT_out;

    // ---- ori projection (gates ms) ----
    proj_a<<<dim3(512), 256, 0, stream>>>(codeB, WallT, go);

    // ---- FI projection co-scheduled with maxscore ----
    projfi_ms<<<dim3(1280), 256, 0, stream>>>(codeB, WallT, go, q_ori, k_ori, maxscT);

    // ---- attn co-scheduled with saoo ----
    AttnArgs aa;
    aa.qT[0]=qT_in;  aa.qT[1]=qT_out;
    aa.kp[0]=k_in;   aa.kp[1]=k_out;
    aa.vT[0]=vT_in;  aa.vT[1]=vT_out;
    attn_saoo<<<dim3(640), 256, 0, stream>>>(aa, sentB, incp, maxscT, codeT, out);
}

// Round 16
// 124.294 us; speedup vs baseline: 1.1448x; 1.1448x over previous
//
#include <hip/hip_runtime.h>
#include <cfloat>

#define B_  16
#define N_  500   // INPUT_SIZE
#define NP  512   // padded N
#define S_  128   // SENTENCE_SIZE
#define D_  512
#define FO  128   // ori head dim
#define FI  64    // in/out head dim

typedef unsigned short u16;
typedef __attribute__((ext_vector_type(8))) short bf8;
typedef __attribute__((ext_vector_type(4))) float f4;

#define MFMA(a,b,c) __builtin_amdgcn_mfma_f32_16x16x32_bf16((a),(b),(c),0,0,0)

__device__ __forceinline__ u16 f2b(float x){
    union{float f;unsigned u;} v; v.f=x;
    unsigned r = v.u + 0x7fffu + ((v.u>>16)&1u);
    return (u16)(r>>16);
}
__device__ __forceinline__ float b2f(u16 x){
    union{unsigned u;float f;} v; v.u=((unsigned)x)<<16; return v.f;
}
__device__ __forceinline__ bf8 ldb8(const u16* p){ return *(const bf8*)p; }

// async global->LDS, 16B per lane; lds base must be wave-uniform (HW adds lane*16B)
__device__ __forceinline__ void gl2lds16(const u16* g, u16* lds){
    __builtin_amdgcn_global_load_lds(
        (const __attribute__((address_space(1))) unsigned int*)g,
        (__attribute__((address_space(3))) unsigned int*)lds, 16, 0, 0);
}

// =====================================================================
// prep_fused: code/weight transposes + sent prep + pad zeroing, 1 launch.
// =====================================================================
struct PWAll { const float* W[8]; u16* WT[8]; };
__global__ __launch_bounds__(256) void prep_fused(const float* __restrict__ code,
                                                  u16* __restrict__ codeB,
                                                  u16* __restrict__ codeT,
                                                  PWAll a,
                                                  const float* __restrict__ sent,
                                                  u16* __restrict__ sentB,
                                                  float* __restrict__ inc,
                                                  u16* a0, u16* a1, u16* a2, u16* a3)
{
    __shared__ float T[64][65];
    const int t = threadIdx.x;
    const int x = blockIdx.x;
    if (x < 1024){
        const int b  = x >> 6;
        const int m0 = ((x >> 3) & 7) * 64;
        const int d0 = (x & 7) * 64;
        #pragma unroll
        for (int i=0;i<16;++i){
            int idx = t + i*256; int rr = idx>>6, cc = idx&63;
            int m = m0+rr;
            T[rr][cc] = (m < N_) ? code[((size_t)b*N_+m)*D_ + d0+cc] : 0.f;
        }
        __syncthreads();
        #pragma unroll
        for (int i=0;i<16;++i){
            int idx=t+i*256; int rr=idx>>6, cc=idx&63; int m=m0+rr;
            if (m<N_) codeB[((size_t)b*N_+m)*D_ + d0+cc] = f2b(T[rr][cc]);
        }
        #pragma unroll
        for (int i=0;i<16;++i){
            int idx=t+i*256; int dd=idx>>6, mm=idx&63;
            codeT[((size_t)b*D_ + d0+dd)*NP + m0+mm] = f2b(T[mm][dd]);
        }
    } else if (x < 1344){
        const int v    = x - 1024;
        const int h    = v / 80;
        const int rem  = v - h*80;
        const int slot = rem >> 3;
        const int d0   = (rem & 7) * 64;
        const int widx = slot<4 ? (slot>>1) : slot-2;
        const int ftile= slot<4 ? (slot&1)  : 0;
        const int F    = slot<4 ? 128 : 64;
        const float* W = a.W[widx];
        u16* WT        = a.WT[widx];
        const int f0 = ftile*64;
        #pragma unroll
        for (int i=0;i<16;++i){
            int idx=t+i*256; int rr=idx>>6, cc=idx&63;
            T[rr][cc] = W[((size_t)h*D_ + d0+rr)*F + f0+cc];
        }
        __syncthreads();
        #pragma unroll
        for (int i=0;i<16;++i){
            int idx=t+i*256; int ff=idx>>6, dd=idx&63;
            WT[((size_t)h*F + f0+ff)*D_ + d0+dd] = f2b(T[dd][ff]);
        }
    } else if (x < 2368){
        const int y  = x - 1344;
        const int b  = y >> 6;
        const int s  = (y & 63)*2 + (t >> 7);
        const int tl = t & 127;
        const float* row = sent + ((size_t)b*S_+s)*N_;
        float4 v = make_float4(0.f,0.f,0.f,0.f);
        const int n = tl*4;
        if (n < N_) v = *(const float4*)(row+n);
        float sum = v.x+v.y+v.z+v.w;
        ushort4 o; o.x=f2b(v.x); o.y=f2b(v.y); o.z=f2b(v.z); o.w=f2b(v.w);
        *(ushort4*)&sentB[((size_t)b*S_+s)*NP + n] = o;
        #pragma unroll
        for (int off=32; off; off>>=1) sum += __shfl_down(sum, off);
        __shared__ float ls[4];
        if ((t&63)==0) ls[t>>6]=sum;
        __syncthreads();
        if (tl==0) inc[b*S_+s] = ls[(t>>7)*2] + ls[(t>>7)*2+1];
    } else {
        const int u  = x - 2368;
        u16* arr4[4] = {a0,a1,a2,a3};
        u16* base = arr4[u>>6] + (size_t)(u&63)*FI*NP;
        for (int idx=t; idx<FI*12; idx+=256){
            int f = idx/12, n = N_ + idx%12;
            base[(size_t)f*NP + n] = 0;
        }
    }
}

// =====================================================================
// proj_gemm: C[8192 x 2560] = codeB @ WallT^T, K=512, bias+relu epilogue.
// 128x128 tile, 4 waves. 3-buffer depth-2 counted-vmcnt modulo pipeline:
// fully unrolled 16 K-steps, LITERAL buffer indices, raw s_barrier,
// vmcnt(8) steady / 4 / 0 tail. Source-chunk XOR swizzle, XCD-chunked
// block swizzle, LDS-staged coalesced stores.
// grid 1280 (64 row-tiles x 20 col-tiles), block 256.
// =====================================================================
struct GemmOut { const float* bias[8]; u16* dst[8]; };
union ProjLDS {
    u16 ab[6][4096];   // A0,A1,A2,B0,B1,B2 (each 128 rows x 32 k, linear)
    u16 ot[16896];     // 128x132 output staging tile
};

#define PG_WAIT(NN) asm volatile("s_waitcnt vmcnt(" #NN ")" ::: "memory")
#define PG_FENCE()  asm volatile("" ::: "memory")

#define PG_STAGE(ai, bi, kk) { \
    gl2lds16(codeB + (size_t)(r0 + w*32      + srow)*D_ + (kk) + cgs, &L.ab[ai][(w*32)*32]);     \
    gl2lds16(WallT + (size_t)(c0 + w*32      + srow)*D_ + (kk) + cgs, &L.ab[bi][(w*32)*32]);     \
    gl2lds16(codeB + (size_t)(r0 + w*32 + 16 + srow)*D_ + (kk) + cgs, &L.ab[ai][(w*32+16)*32]);  \
    gl2lds16(WallT + (size_t)(c0 + w*32 + 16 + srow)*D_ + (kk) + cgs, &L.ab[bi][(w*32+16)*32]);  \
}

#define PG_COMPUTE(ai, bi) { \
    bf8 af[4], bfr[4]; \
    _Pragma("unroll") \
    for (int i=0;i<4;++i){ \
        af[i]  = *(const bf8*)&L.ab[ai][(wr + i*16 + lane16)*32 + kread]; \
        bfr[i] = *(const bf8*)&L.ab[bi][(wc + i*16 + lane16)*32 + kread]; \
    } \
    _Pragma("unroll") \
    for (int i=0;i<4;++i) \
        _Pragma("unroll") \
        for (int j=0;j<4;++j) \
            acc[i][j] = MFMA(af[i], bfr[j], acc[i][j]); \
}

#define PG_STEP(WN, ai, bi, jn) { \
    PG_WAIT(WN); \
    __builtin_amdgcn_s_barrier(); \
    PG_FENCE(); \
    __builtin_amdgcn_s_setprio(1); \
    PG_COMPUTE(ai, bi); \
    __builtin_amdgcn_s_setprio(0); \
    __builtin_amdgcn_s_barrier(); \
    PG_FENCE(); \
    if ((jn) < 16) PG_STAGE(ai, bi, (jn)*32); \
}

__global__ __launch_bounds__(256) void proj_gemm(const u16* __restrict__ codeB,
                                                 const u16* __restrict__ WallT,
                                                 GemmOut go)
{
    __shared__ alignas(16) ProjLDS L;

    const int t = threadIdx.x;
    const int w = t>>6, l = t&63, lane16 = l&15, lq = l>>4;
    const int bid = blockIdx.x;
    const int xcd = bid & 7;
    const int g   = bid >> 3;          // 0..159
    const int rt  = xcd*8 + g/20;      // 0..63
    const int ct  = g - (g/20)*20;     // 0..19
    const int r0 = rt*128;
    const int c0 = ct*128;
    const int wr = (w>>1)*64, wc = (w&1)*64;
    const int srow = l>>2;                              // staging row in 16-row issue
    const int cgs  = ((l&3) ^ ((srow>>1)&3))*8;         // swizzled source chunk (u16)
    const int kread= (lq ^ ((lane16>>1)&3))*8;          // swizzled read chunk (u16)

    f4 acc[4][4] = {};

    // prologue: stage steps 0,1,2
    PG_STAGE(0,3, 0);
    PG_STAGE(1,4, 32);
    PG_STAGE(2,5, 64);

    // 16 steps, buffers cycle 0/1/2 (A) and 3/4/5 (B); stage step j+3 after compute
    PG_STEP(8, 0,3, 3);    // j=0
    PG_STEP(8, 1,4, 4);
    PG_STEP(8, 2,5, 5);
    PG_STEP(8, 0,3, 6);
    PG_STEP(8, 1,4, 7);
    PG_STEP(8, 2,5, 8);
    PG_STEP(8, 0,3, 9);
    PG_STEP(8, 1,4, 10);
    PG_STEP(8, 2,5, 11);
    PG_STEP(8, 0,3, 12);
    PG_STEP(8, 1,4, 13);
    PG_STEP(8, 2,5, 14);
    PG_STEP(8, 0,3, 15);
    PG_STEP(8, 1,4, 16);   // j=13 (no stage)
    PG_STEP(4, 2,5, 17);   // j=14 (no stage)
    PG_STEP(0, 0,3, 18);   // j=15 (no stage)

    // region of this col-tile
    const int ri = (ct<4) ? 0 : (ct<8) ? 1 : 2 + ((ct-8)>>1);
    const bool tr = (ri==2)||(ri==4)||(ri==5)||(ri==7);

    __syncthreads();   // full drain before L.ot reuse

    // ---- stage output tile in LDS (stride 132) ----
    #pragma unroll
    for (int j=0;j<4;++j){
        const int c = c0 + wc + j*16 + lane16;
        const int idx = (c < 1024) ? (c & 511) : ((c-1024) & 255);
        const float bv = go.bias[ri][idx];
        if (tr){
            #pragma unroll
            for (int i=0;i<4;++i){
                ushort4 o4;
                float x0=acc[i][j][0]+bv, x1=acc[i][j][1]+bv, x2=acc[i][j][2]+bv, x3=acc[i][j][3]+bv;
                o4.x=f2b(x0>0.f?x0:0.f); o4.y=f2b(x1>0.f?x1:0.f);
                o4.z=f2b(x2>0.f?x2:0.f); o4.w=f2b(x3>0.f?x3:0.f);
                *(ushort4*)&L.ot[(wc+j*16+lane16)*132 + wr+i*16+lq*4] = o4;
            }
        } else {
            #pragma unroll
            for (int i=0;i<4;++i)
                #pragma unroll
                for (int reg=0;reg<4;++reg){
                    float x = acc[i][j][reg] + bv;
                    L.ot[(wr+i*16+lq*4+reg)*132 + wc+j*16+lane16] = f2b(x>0.f?x:0.f);
                }
        }
    }
    __syncthreads();

    // ---- coalesced global stores ----
    if (tr){
        const int c  = t>>1;
        const int cg = c0 + c;
        const int u  = cg - 1024;
        const int hfv = u & 255, h = hfv>>6, f2 = hfv & 63;
        u16* dbase = go.dst[ri];
        const int half = t & 1;
        #pragma unroll
        for (int k2=0;k2<16;++k2){
            const int r  = half*64 + k2*4;
            const int rb = r0 + r;
            if (rb < 8000){
                const int b = rb/500, n = rb - b*500;
                *(ushort4*)&dbase[((size_t)(b*4+h)*FI + f2)*NP + n] =
                    *(const ushort4*)&L.ot[c*132 + r];
            }
        }
    } else {
        const int r  = t>>1;
        const int rb = r0 + r;
        if (rb < 8000){
            const int b = rb/500, n = rb - b*500;
            const int half = t & 1;
            const int cg0 = c0 + half*64;
            int h, f2base, F2;
            if (cg0 < 1024){ const int hf0 = cg0 & 511; h = hf0>>7; f2base = hf0 & 127; F2 = 128; }
            else           { const int hf0 = (cg0-1024) & 255; h = hf0>>6; f2base = hf0 & 63; F2 = 64; }
            u16* dstp = go.dst[ri] + ((size_t)(b*4+h)*N_ + n)*F2 + f2base;
            #pragma unroll
            for (int k2=0;k2<16;++k2)
                *(ushort4*)&dstp[k2*4] = *(const ushort4*)&L.ot[r*132 + half*64 + k2*4];
        }
    }
}

// =====================================================================
// msattn: ms_mfma and attn_fused fused into one launch (independent work).
// grid 1024, block 256: even blocks -> ms (idx=x>>1), odd -> attn.
// =====================================================================
struct AttnArgs { const u16* qT[2]; const u16* kp[2]; const u16* vT[2]; };
struct MsLDS  { u16 Qs[64][136]; u16 Ks[128][136]; };
struct AtLDS  { float red[4][32][68]; u16 qsS[32][72]; u16 Pw[4][32][72]; };
union MALDS   { MsLDS ms; AtLDS at; };

__global__ __launch_bounds__(256) void msattn(const u16* __restrict__ q,
                                              const u16* __restrict__ k,
                                              u16* __restrict__ maxscT,
                                              AttnArgs a,
                                              const u16* __restrict__ sentB,
                                              const float* __restrict__ inc,
                                              float* __restrict__ out)
{
    __shared__ alignas(16) MALDS L;
    const int t=threadIdx.x, w=t>>6, l=t&63, lane16=l&15, lq=l>>4;
    const int idx = blockIdx.x >> 1;

    if ((blockIdx.x & 1) == 0){
        // ---------------- ms part ----------------
        const int b=idx&15, n0=((idx>>4)&7)*64, m0=(idx>>7)*128;
        const int wr=(w>>1)*32, wc=(w&1)*64;

        f4 best[2][4];
        #pragma unroll
        for(int rt=0;rt<2;++rt)
            #pragma unroll
            for(int ct=0;ct<4;++ct)
                #pragma unroll
                for(int i=0;i<4;++i) best[rt][ct][i] = -FLT_MAX;

        for (int h=0;h<4;++h){
            const u16* qh = q + (size_t)(b*4+h)*N_*FO;
            const u16* kh = k + (size_t)(b*4+h)*N_*FO;
            #pragma unroll
            for (int i=0;i<4;++i){
                const int e=t+i*256, row=e>>4, kc=(e&15)*8;
                int n=n0+row; if(n>N_-1)n=N_-1;
                *(bf8*)&L.ms.Qs[row][kc] = ldb8(qh + (size_t)n*FO + kc);
            }
            #pragma unroll
            for (int i=0;i<8;++i){
                const int e=t+i*256, row=e>>4, kc=(e&15)*8;
                int m=m0+row; if(m>N_-1)m=N_-1;
                *(bf8*)&L.ms.Ks[row][kc] = ldb8(kh + (size_t)m*FO + kc);
            }
            __syncthreads();
            f4 acc[2][4]={};
            #pragma unroll
            for (int kk=0;kk<FO;kk+=32){
                bf8 a0=*(const bf8*)&L.ms.Qs[wr+lane16][kk+lq*8];
                bf8 a1=*(const bf8*)&L.ms.Qs[wr+16+lane16][kk+lq*8];
                #pragma unroll
                for(int ct=0;ct<4;++ct){
                    bf8 bb=*(const bf8*)&L.ms.Ks[wc+ct*16+lane16][kk+lq*8];
                    acc[0][ct]=MFMA(a0,bb,acc[0][ct]);
                    acc[1][ct]=MFMA(a1,bb,acc[1][ct]);
                }
            }
            #pragma unroll
            for(int rt=0;rt<2;++rt)
                #pragma unroll
                for(int ct=0;ct<4;++ct)
                    #pragma unroll
                    for(int i=0;i<4;++i) best[rt][ct][i] = fmaxf(best[rt][ct][i], acc[rt][ct][i]);
            __syncthreads();
        }
        #pragma unroll
        for(int rt=0;rt<2;++rt)
            #pragma unroll
            for(int ct=0;ct<4;++ct){
                const int m  = m0+wc+ct*16+lane16;
                const int nb = n0+wr+rt*16+lq*4;
                ushort4 o; o.x=f2b(best[rt][ct][0]); o.y=f2b(best[rt][ct][1]);
                o.z=f2b(best[rt][ct][2]); o.w=f2b(best[rt][ct][3]);
                *(ushort4*)&maxscT[((size_t)b*NP+m)*NP + nb] = o;
            }
    } else {
        // ---------------- attn part ----------------
        const int bh=idx&63, b=bh>>2, h=bh&3, s0=((idx>>6)&3)*32, br=idx>>8;
        const u16* qT = a.qT[br];
        const u16* kp = a.kp[br];
        const u16* vT = a.vT[br];

        { // phase 1: qs partial, k-range [w*128, w*128+128)
            const u16 *ap[2], *bp[4];
            #pragma unroll
            for(int rt=0;rt<2;++rt) ap[rt] = sentB + ((size_t)b*S_ + s0+rt*16+lane16)*NP + w*128 + lq*8;
            #pragma unroll
            for(int ct=0;ct<4;++ct) bp[ct] = qT + ((size_t)bh*FI + ct*16+lane16)*NP + w*128 + lq*8;
            f4 acc[2][4] = {};
            #pragma unroll
            for (int k0=0;k0<128;k0+=32){
                bf8 a0=ldb8(ap[0]+k0), a1=ldb8(ap[1]+k0);
                #pragma unroll
                for(int ct=0;ct<4;++ct){
                    bf8 bb=ldb8(bp[ct]+k0);
                    acc[0][ct]=MFMA(a0,bb,acc[0][ct]);
                    acc[1][ct]=MFMA(a1,bb,acc[1][ct]);
                }
            }
            #pragma unroll
            for(int rt=0;rt<2;++rt)
                #pragma unroll
                for(int ct=0;ct<4;++ct)
                    #pragma unroll
                    for(int reg=0;reg<4;++reg)
                        L.at.red[w][rt*16+lq*4+reg][ct*16+lane16] = acc[rt][ct][reg];
        }
        __syncthreads();
        {
            const int s=t>>3, f0=(t&7)*8;
            #pragma unroll
            for (int j=0;j<8;++j){
                float v = L.at.red[0][s][f0+j]+L.at.red[1][s][f0+j]
                        + L.at.red[2][s][f0+j]+L.at.red[3][s][f0+j];
                L.at.qsS[s][f0+j] = f2b(v);
            }
        }
        __syncthreads();

        f4 accO[2][4] = {};
        #pragma unroll
        for (int c=0;c<2;++c){
            const int m0 = w*64 + c*256;
            f4 p[2][4] = {};
            const u16* bp[4];
            #pragma unroll
            for(int ct=0;ct<4;++ct){
                int m=m0+ct*16+lane16; if(m>N_-1)m=N_-1;
                bp[ct] = kp + ((size_t)bh*N_+m)*FI + lq*8;
            }
            #pragma unroll
            for (int kk=0; kk<FI; kk+=32){
                bf8 a0 = *(const bf8*)&L.at.qsS[lane16][kk+lq*8];
                bf8 a1 = *(const bf8*)&L.at.qsS[16+lane16][kk+lq*8];
                #pragma unroll
                for(int ct=0;ct<4;++ct){
                    bf8 bb=ldb8(bp[ct]+kk);
                    p[0][ct]=MFMA(a0,bb,p[0][ct]);
                    p[1][ct]=MFMA(a1,bb,p[1][ct]);
                }
            }
            #pragma unroll
            for(int rt=0;rt<2;++rt)
                #pragma unroll
                for(int ct=0;ct<4;++ct){
                    const int m = m0+ct*16+lane16;
                    #pragma unroll
                    for(int reg=0;reg<4;++reg){
                        const int s = s0+rt*16+lq*4+reg;
                        const float sv = b2f(sentB[((size_t)b*S_+s)*NP+m]);
                        const float wgt = br ? ((m<N_)? sv-1.f : 0.f) : sv;
                        L.at.Pw[w][rt*16+lq*4+reg][ct*16+lane16] = f2b(p[rt][ct][reg]*wgt);
                    }
                }
            #pragma unroll
            for (int kk2=0; kk2<64; kk2+=32){
                bf8 a2[2];
                #pragma unroll
                for(int rt=0;rt<2;++rt) a2[rt] = *(const bf8*)&L.at.Pw[w][rt*16+lane16][kk2+lq*8];
                #pragma unroll
                for(int ct=0;ct<4;++ct){
                    bf8 vv = ldb8(vT + ((size_t)bh*FI + ct*16+lane16)*NP + m0+kk2+lq*8);
                    accO[0][ct]=MFMA(a2[0],vv,accO[0][ct]);
                    accO[1][ct]=MFMA(a2[1],vv,accO[1][ct]);
                }
            }
        }
        #pragma unroll
        for(int rt=0;rt<2;++rt)
            #pragma unroll
            for(int ct=0;ct<4;++ct)
                #pragma unroll
                for(int reg=0;reg<4;++reg)
                    L.at.red[w][rt*16+lq*4+reg][ct*16+lane16] = accO[rt][ct][reg];
        __syncthreads();
        {
            const int s=t>>3, f0=(t&7)*8;
            float fac = 1.f;
            if (br){ const float ic = inc[b*S_+s0+s]; fac = ic/(500.f-ic); }
            const size_t o = ((size_t)b*S_+s0+s)*1024 + (br?768:512) + h*FI + f0;
            #pragma unroll
            for (int j=0;j<8;++j){
                float v = L.at.red[0][s][f0+j]+L.at.red[1][s][f0+j]
                        + L.at.red[2][s][f0+j]+L.at.red[3][s][f0+j];
                out[o+j] = v*fac;
            }
        }
    }
}

// =====================================================================
// saoo: fused  sAm = sent ⊙ (sent @ maxscT)  then  out_ori = sAm @ code
// grid (16 b, 8 stile16), block 512 (8 waves).
// =====================================================================
__global__ __launch_bounds__(512) void saoo(const u16* __restrict__ sentB,
                                            const u16* __restrict__ maxscT,
                                            const u16* __restrict__ codeT,
                                            float* __restrict__ out)
{
    __shared__ u16 sAmS[16][520];
    const int b=blockIdx.x, s0=blockIdx.y*16;
    const int t=threadIdx.x, w=t>>6, l=t&63, lane16=l&15, lq=l>>4;

    { // phase 1: m-chunk w
        const int m0 = w*64;
        const u16* ap = sentB + ((size_t)b*S_ + s0+lane16)*NP + lq*8;
        const u16* bp[4];
        #pragma unroll
        for(int ct=0;ct<4;++ct) bp[ct] = maxscT + ((size_t)b*NP + m0+ct*16+lane16)*NP + lq*8;
        f4 acc[4] = {};
        for (int k0=0;k0<NP;k0+=32){
            bf8 av=ldb8(ap+k0);
            #pragma unroll
            for(int ct=0;ct<4;++ct) acc[ct]=MFMA(av, ldb8(bp[ct]+k0), acc[ct]);
        }
        #pragma unroll
        for(int ct=0;ct<4;++ct){
            const int m = m0+ct*16+lane16;
            #pragma unroll
            for(int reg=0;reg<4;++reg){
                const int s = s0+lq*4+reg;
                const float sv = b2f(sentB[((size_t)b*S_+s)*NP+m]);
                sAmS[lq*4+reg][m] = (sv != 0.f) ? f2b(acc[ct][reg]*sv) : (u16)0;
            }
        }
    }
    __syncthreads();
    { // phase 2: d-chunk w
        const int d0 = w*64;
        const u16* bp[4];
        #pragma unroll
        for(int ct=0;ct<4;++ct) bp[ct] = codeT + ((size_t)b*D_ + d0+ct*16+lane16)*NP + lq*8;
        f4 acc[4] = {};
        for (int k0=0;k0<NP;k0+=32){
            bf8 av = *(const bf8*)&sAmS[lane16][k0+lq*8];
            #pragma unroll
            for(int ct=0;ct<4;++ct) acc[ct]=MFMA(av, ldb8(bp[ct]+k0), acc[ct]);
        }
        #pragma unroll
        for(int ct=0;ct<4;++ct){
            const int d = d0+ct*16+lane16;
            #pragma unroll
            for(int reg=0;reg<4;++reg){
                const int s = s0+lq*4+reg;
                out[((size_t)b*S_+s)*1024 + d] = acc[ct][reg];
            }
        }
    }
}

// =====================================================================
extern "C" void kernel_launch(void* const* d_in, const int* in_sizes, int n_in,
                              void* d_out, int out_size, void* d_ws, size_t ws_size,
                              hipStream_t stream)
{
    const float* code   = (const float*)d_in[0];
    const float* sent   = (const float*)d_in[1];
    const float* Wq_ori = (const float*)d_in[2];
    const float* bq_ori = (const float*)d_in[3];
    const float* Wk_ori = (const float*)d_in[4];
    const float* bk_ori = (const float*)d_in[5];
    const float* Wq_in  = (const float*)d_in[6];
    const float* bq_in  = (const float*)d_in[7];
    const float* Wk_in  = (const float*)d_in[8];
    const float* bk_in  = (const float*)d_in[9];
    const float* Wv_in  = (const float*)d_in[10];
    const float* bv_in  = (const float*)d_in[11];
    const float* Wq_out = (const float*)d_in[12];
    const float* bq_out = (const float*)d_in[13];
    const float* Wk_out = (const float*)d_in[14];
    const float* bk_out = (const float*)d_in[15];
    const float* Wv_out = (const float*)d_in[16];
    const float* bv_out = (const float*)d_in[17];
    float* out = (float*)d_out;

    // fully disjoint workspace (~71 MB; ws is ~268 MB)
    char* w = (char*)d_ws;
    u16*   codeB  = (u16*)(w);                  // 8192*512*2 = 8,388,608 B
    u16*   WallT  = (u16*)(w + 8388608);        // 2560*512*2 = 2,621,440 B
    u16*   WTqo   = WallT;
    u16*   WTko   = WallT +  262144;
    u16*   WTqi   = WallT +  524288;
    u16*   WTki   = WallT +  655360;
    u16*   WTvi   = WallT +  786432;
    u16*   WTqu   = WallT +  917504;
    u16*   WTku   = WallT + 1048576;
    u16*   WTvu   = WallT + 1179648;
    u16*   sentB  = (u16*)(w + 11010048);       // 2,097,152
    float* incp   = (float*)(w + 13107200);     // 8,192
    u16* q_ori  = (u16*)(w + 13115392);         // 8,192,000
    u16* k_ori  = (u16*)(w + 21307392);         // 8,192,000
    u16* maxscT = (u16*)(w + 29499392);         // 8,388,608
    u16* codeT  = (u16*)(w + 37888000);         // 8,388,608
    u16* k_in   = (u16*)(w + 46276608);         // 4,096,000
    u16* k_out  = (u16*)(w + 50372608);         // 4,096,000
    u16* qT_in  = (u16*)(w + 54468608);         // 4,194,304
    u16* qT_out = (u16*)(w + 58662912);
    u16* vT_in  = (u16*)(w + 62857216);
    u16* vT_out = (u16*)(w + 67051520);         // ends 71,245,824

    // ---- prep (1 launch) ----
    PWAll pw;
    pw.W[0]=Wq_ori; pw.W[1]=Wk_ori; pw.W[2]=Wq_in; pw.W[3]=Wk_in;
    pw.W[4]=Wv_in;  pw.W[5]=Wq_out; pw.W[6]=Wk_out; pw.W[7]=Wv_out;
    pw.WT[0]=WTqo; pw.WT[1]=WTko; pw.WT[2]=WTqi; pw.WT[3]=WTki;
    pw.WT[4]=WTvi; pw.WT[5]=WTqu; pw.WT[6]=WTku; pw.WT[7]=WTvu;
    prep_fused<<<dim3(2624), 256, 0, stream>>>(code, codeB, codeT, pw,
                                               sent, sentB, incp,
                                               qT_in, qT_out, vT_in, vT_out);

    // ---- single projection GEMM for all 20 col-tiles ----
    GemmOut go;
    go.bias[0]=bq_ori; go.bias[1]=bk_ori; go.bias[2]=bq_in; go.bias[3]=bk_in;
    go.bias[4]=bv_in;  go.bias[5]=bq_out; go.bias[6]=bk_out; go.bias[7]=bv_out;
    go.dst[0]=q_ori; go.dst[1]=k_ori; go.dst[2]=qT_in; go.dst[3]=k_in;
    go.dst[4]=vT_in; go.dst[5]=qT_out; go.dst[6]=k_out; go.dst[7]=vT_out;
    proj_gemm<<<dim3(1280), 256, 0, stream>>>(codeB, WallT, go);

    // ---- ms + attn fused (independent work, co-scheduled) ----
    AttnArgs aa;
    aa.qT[0]=qT_in;  aa.qT[1]=qT_out;
    aa.kp[0]=k_in;   aa.kp[1]=k_out;
    aa.vT[0]=vT_in;  aa.vT[1]=vT_out;
    msattn<<<dim3(1024), 256, 0, stream>>>(q_ori, k_ori, maxscT, aa, sentB, incp, out);

    // ---- ori epilogue ----
    saoo<<<dim3(16,8), 512, 0, stream>>>(sentB, maxscT, codeT, out);
}

// Round 17
// 123.866 us; speedup vs baseline: 1.1488x; 1.0035x over previous
//
#include <hip/hip_runtime.h>
#include <cfloat>

#define B_  16
#define N_  500   // INPUT_SIZE
#define NP  512   // padded N
#define S_  128   // SENTENCE_SIZE
#define D_  512
#define FO  128   // ori head dim
#define FI  64    // in/out head dim

typedef unsigned short u16;
typedef __attribute__((ext_vector_type(8))) short bf8;
typedef __attribute__((ext_vector_type(4))) float f4;

#define MFMA(a,b,c) __builtin_amdgcn_mfma_f32_16x16x32_bf16((a),(b),(c),0,0,0)

__device__ __forceinline__ u16 f2b(float x){
    union{float f;unsigned u;} v; v.f=x;
    unsigned r = v.u + 0x7fffu + ((v.u>>16)&1u);
    return (u16)(r>>16);
}
__device__ __forceinline__ float b2f(u16 x){
    union{unsigned u;float f;} v; v.u=((unsigned)x)<<16; return v.f;
}
__device__ __forceinline__ bf8 ldb8(const u16* p){ return *(const bf8*)p; }

// async global->LDS, 16B per lane; lds base must be wave-uniform (HW adds lane*16B)
__device__ __forceinline__ void gl2lds16(const u16* g, u16* lds){
    __builtin_amdgcn_global_load_lds(
        (const __attribute__((address_space(1))) unsigned int*)g,
        (__attribute__((address_space(3))) unsigned int*)lds, 16, 0, 0);
}

// =====================================================================
// prep_fused: code/weight transposes + sent prep + pad zeroing, 1 launch.
// =====================================================================
struct PWAll { const float* W[8]; u16* WT[8]; };
__global__ __launch_bounds__(256) void prep_fused(const float* __restrict__ code,
                                                  u16* __restrict__ codeB,
                                                  u16* __restrict__ codeT,
                                                  PWAll a,
                                                  const float* __restrict__ sent,
                                                  u16* __restrict__ sentB,
                                                  float* __restrict__ inc,
                                                  u16* a0, u16* a1, u16* a2, u16* a3)
{
    __shared__ float T[64][65];
    const int t = threadIdx.x;
    const int x = blockIdx.x;
    if (x < 1024){
        const int b  = x >> 6;
        const int m0 = ((x >> 3) & 7) * 64;
        const int d0 = (x & 7) * 64;
        #pragma unroll
        for (int i=0;i<16;++i){
            int idx = t + i*256; int rr = idx>>6, cc = idx&63;
            int m = m0+rr;
            T[rr][cc] = (m < N_) ? code[((size_t)b*N_+m)*D_ + d0+cc] : 0.f;
        }
        __syncthreads();
        #pragma unroll
        for (int i=0;i<16;++i){
            int idx=t+i*256; int rr=idx>>6, cc=idx&63; int m=m0+rr;
            if (m<N_) codeB[((size_t)b*N_+m)*D_ + d0+cc] = f2b(T[rr][cc]);
        }
        #pragma unroll
        for (int i=0;i<16;++i){
            int idx=t+i*256; int dd=idx>>6, mm=idx&63;
            codeT[((size_t)b*D_ + d0+dd)*NP + m0+mm] = f2b(T[mm][dd]);
        }
    } else if (x < 1344){
        const int v    = x - 1024;
        const int h    = v / 80;
        const int rem  = v - h*80;
        const int slot = rem >> 3;
        const int d0   = (rem & 7) * 64;
        const int widx = slot<4 ? (slot>>1) : slot-2;
        const int ftile= slot<4 ? (slot&1)  : 0;
        const int F    = slot<4 ? 128 : 64;
        const float* W = a.W[widx];
        u16* WT        = a.WT[widx];
        const int f0 = ftile*64;
        #pragma unroll
        for (int i=0;i<16;++i){
            int idx=t+i*256; int rr=idx>>6, cc=idx&63;
            T[rr][cc] = W[((size_t)h*D_ + d0+rr)*F + f0+cc];
        }
        __syncthreads();
        #pragma unroll
        for (int i=0;i<16;++i){
            int idx=t+i*256; int ff=idx>>6, dd=idx&63;
            WT[((size_t)h*F + f0+ff)*D_ + d0+dd] = f2b(T[dd][ff]);
        }
    } else if (x < 2368){
        const int y  = x - 1344;
        const int b  = y >> 6;
        const int s  = (y & 63)*2 + (t >> 7);
        const int tl = t & 127;
        const float* row = sent + ((size_t)b*S_+s)*N_;
        float4 v = make_float4(0.f,0.f,0.f,0.f);
        const int n = tl*4;
        if (n < N_) v = *(const float4*)(row+n);
        float sum = v.x+v.y+v.z+v.w;
        ushort4 o; o.x=f2b(v.x); o.y=f2b(v.y); o.z=f2b(v.z); o.w=f2b(v.w);
        *(ushort4*)&sentB[((size_t)b*S_+s)*NP + n] = o;
        #pragma unroll
        for (int off=32; off; off>>=1) sum += __shfl_down(sum, off);
        __shared__ float ls[4];
        if ((t&63)==0) ls[t>>6]=sum;
        __syncthreads();
        if (tl==0) inc[b*S_+s] = ls[(t>>7)*2] + ls[(t>>7)*2+1];
    } else {
        const int u  = x - 2368;
        u16* arr4[4] = {a0,a1,a2,a3};
        u16* base = arr4[u>>6] + (size_t)(u&63)*FI*NP;
        for (int idx=t; idx<FI*12; idx+=256){
            int f = idx/12, n = N_ + idx%12;
            base[(size_t)f*NP + n] = 0;
        }
    }
}

// =====================================================================
// proj_gemm: C[8192 x 2560] = codeB @ WallT^T, K=512, bias+relu epilogue.
// 128x128 tile, 4 waves. 3-buffer counted-vmcnt modulo pipeline with ONE
// barrier per K-step: {vmcnt(4); s_barrier; stage(j+2); compute(j)}.
// Safety: stage(j+2) targets buffer (j-1)%3 whose last reader, compute(j-1),
// completed in every wave before the step-j barrier (it is the final op of
// step j-1); a fast wave's stage(j+3) into buffer j%3 is blocked by
// barrier j+1. Source-chunk XOR swizzle, XCD-chunked block swizzle,
// LDS-staged coalesced stores. grid 1280, block 256.
// =====================================================================
struct GemmOut { const float* bias[8]; u16* dst[8]; };
union ProjLDS {
    u16 ab[6][4096];   // A0,A1,A2,B0,B1,B2 (each 128 rows x 32 k, linear)
    u16 ot[16896];     // 128x132 output staging tile
};

#define PG_WAIT(NN) asm volatile("s_waitcnt vmcnt(" #NN ")" ::: "memory")
#define PG_FENCE()  asm volatile("" ::: "memory")

#define PG_STAGE(ai, bi, kk) { \
    gl2lds16(codeB + (size_t)(r0 + w*32      + srow)*D_ + (kk) + cgs, &L.ab[ai][(w*32)*32]);     \
    gl2lds16(WallT + (size_t)(c0 + w*32      + srow)*D_ + (kk) + cgs, &L.ab[bi][(w*32)*32]);     \
    gl2lds16(codeB + (size_t)(r0 + w*32 + 16 + srow)*D_ + (kk) + cgs, &L.ab[ai][(w*32+16)*32]);  \
    gl2lds16(WallT + (size_t)(c0 + w*32 + 16 + srow)*D_ + (kk) + cgs, &L.ab[bi][(w*32+16)*32]);  \
}

#define PG_COMPUTE(ai, bi) { \
    bf8 af[4], bfr[4]; \
    _Pragma("unroll") \
    for (int i=0;i<4;++i){ \
        af[i]  = *(const bf8*)&L.ab[ai][(wr + i*16 + lane16)*32 + kread]; \
        bfr[i] = *(const bf8*)&L.ab[bi][(wc + i*16 + lane16)*32 + kread]; \
    } \
    _Pragma("unroll") \
    for (int i=0;i<4;++i) \
        _Pragma("unroll") \
        for (int j=0;j<4;++j) \
            acc[i][j] = MFMA(af[i], bfr[j], acc[i][j]); \
}

// one barrier per step; sa/sb = buffers being staged for step j+2 (or -1 = none)
#define PG_STEP1(WN, ai, bi, sa, sb, jn) { \
    PG_WAIT(WN); \
    __builtin_amdgcn_s_barrier(); \
    PG_FENCE(); \
    if ((jn) < 16) PG_STAGE(sa, sb, (jn)*32); \
    __builtin_amdgcn_s_setprio(1); \
    PG_COMPUTE(ai, bi); \
    __builtin_amdgcn_s_setprio(0); \
    PG_FENCE(); \
}

__global__ __launch_bounds__(256) void proj_gemm(const u16* __restrict__ codeB,
                                                 const u16* __restrict__ WallT,
                                                 GemmOut go)
{
    __shared__ alignas(16) ProjLDS L;

    const int t = threadIdx.x;
    const int w = t>>6, l = t&63, lane16 = l&15, lq = l>>4;
    const int bid = blockIdx.x;
    const int xcd = bid & 7;
    const int g   = bid >> 3;          // 0..159
    const int rt  = xcd*8 + g/20;      // 0..63
    const int ct  = g - (g/20)*20;     // 0..19
    const int r0 = rt*128;
    const int c0 = ct*128;
    const int wr = (w>>1)*64, wc = (w&1)*64;
    const int srow = l>>2;                              // staging row in 16-row issue
    const int cgs  = ((l&3) ^ ((srow>>1)&3))*8;         // swizzled source chunk (u16)
    const int kread= (lq ^ ((lane16>>1)&3))*8;          // swizzled read chunk (u16)

    f4 acc[4][4] = {};

    // prologue: stage steps 0,1
    PG_STAGE(0,3, 0);
    PG_STAGE(1,4, 32);

    // 16 steps, buffers cycle 0/1/2 (A) and 3/4/5 (B); stage step j+2 after
    // the step-j barrier (before compute). steady wait = stage j+1 in flight (4).
    PG_STEP1(4, 0,3, 2,5, 2);    // j=0:  stage 2
    PG_STEP1(4, 1,4, 0,3, 3);    // j=1:  stage 3
    PG_STEP1(4, 2,5, 1,4, 4);    // j=2:  stage 4
    PG_STEP1(4, 0,3, 2,5, 5);    // j=3
    PG_STEP1(4, 1,4, 0,3, 6);    // j=4
    PG_STEP1(4, 2,5, 1,4, 7);    // j=5
    PG_STEP1(4, 0,3, 2,5, 8);    // j=6
    PG_STEP1(4, 1,4, 0,3, 9);    // j=7
    PG_STEP1(4, 2,5, 1,4, 10);   // j=8
    PG_STEP1(4, 0,3, 2,5, 11);   // j=9
    PG_STEP1(4, 1,4, 0,3, 12);   // j=10
    PG_STEP1(4, 2,5, 1,4, 13);   // j=11
    PG_STEP1(4, 0,3, 2,5, 14);   // j=12
    PG_STEP1(4, 1,4, 0,3, 15);   // j=13: stage 15 (last)
    PG_STEP1(4, 2,5, 0,3, 16);   // j=14: no stage
    PG_STEP1(0, 0,3, 0,3, 16);   // j=15: no stage, full drain

    // region of this col-tile
    const int ri = (ct<4) ? 0 : (ct<8) ? 1 : 2 + ((ct-8)>>1);
    const bool tr = (ri==2)||(ri==4)||(ri==5)||(ri==7);

    __syncthreads();   // full drain before L.ot reuse

    // ---- stage output tile in LDS (stride 132) ----
    #pragma unroll
    for (int j=0;j<4;++j){
        const int c = c0 + wc + j*16 + lane16;
        const int idx = (c < 1024) ? (c & 511) : ((c-1024) & 255);
        const float bv = go.bias[ri][idx];
        if (tr){
            #pragma unroll
            for (int i=0;i<4;++i){
                ushort4 o4;
                float x0=acc[i][j][0]+bv, x1=acc[i][j][1]+bv, x2=acc[i][j][2]+bv, x3=acc[i][j][3]+bv;
                o4.x=f2b(x0>0.f?x0:0.f); o4.y=f2b(x1>0.f?x1:0.f);
                o4.z=f2b(x2>0.f?x2:0.f); o4.w=f2b(x3>0.f?x3:0.f);
                *(ushort4*)&L.ot[(wc+j*16+lane16)*132 + wr+i*16+lq*4] = o4;
            }
        } else {
            #pragma unroll
            for (int i=0;i<4;++i)
                #pragma unroll
                for (int reg=0;reg<4;++reg){
                    float x = acc[i][j][reg] + bv;
                    L.ot[(wr+i*16+lq*4+reg)*132 + wc+j*16+lane16] = f2b(x>0.f?x:0.f);
                }
        }
    }
    __syncthreads();

    // ---- coalesced global stores ----
    if (tr){
        const int c  = t>>1;
        const int cg = c0 + c;
        const int u  = cg - 1024;
        const int hfv = u & 255, h = hfv>>6, f2 = hfv & 63;
        u16* dbase = go.dst[ri];
        const int half = t & 1;
        #pragma unroll
        for (int k2=0;k2<16;++k2){
            const int r  = half*64 + k2*4;
            const int rb = r0 + r;
            if (rb < 8000){
                const int b = rb/500, n = rb - b*500;
                *(ushort4*)&dbase[((size_t)(b*4+h)*FI + f2)*NP + n] =
                    *(const ushort4*)&L.ot[c*132 + r];
            }
        }
    } else {
        const int r  = t>>1;
        const int rb = r0 + r;
        if (rb < 8000){
            const int b = rb/500, n = rb - b*500;
            const int half = t & 1;
            const int cg0 = c0 + half*64;
            int h, f2base, F2;
            if (cg0 < 1024){ const int hf0 = cg0 & 511; h = hf0>>7; f2base = hf0 & 127; F2 = 128; }
            else           { const int hf0 = (cg0-1024) & 255; h = hf0>>6; f2base = hf0 & 63; F2 = 64; }
            u16* dstp = go.dst[ri] + ((size_t)(b*4+h)*N_ + n)*F2 + f2base;
            #pragma unroll
            for (int k2=0;k2<16;++k2)
                *(ushort4*)&dstp[k2*4] = *(const ushort4*)&L.ot[r*132 + half*64 + k2*4];
        }
    }
}

// =====================================================================
// msattn: ms_mfma and attn_fused fused into one launch (independent work).
// grid 1024, block 256: even blocks -> ms (idx=x>>1), odd -> attn.
// =====================================================================
struct AttnArgs { const u16* qT[2]; const u16* kp[2]; const u16* vT[2]; };
struct MsLDS  { u16 Qs[64][136]; u16 Ks[128][136]; };
struct AtLDS  { float red[4][32][68]; u16 qsS[32][72]; u16 Pw[4][32][72]; };
union MALDS   { MsLDS ms; AtLDS at; };

__global__ __launch_bounds__(256) void msattn(const u16* __restrict__ q,
                                              const u16* __restrict__ k,
                                              u16* __restrict__ maxscT,
                                              AttnArgs a,
                                              const u16* __restrict__ sentB,
                                              const float* __restrict__ inc,
                                              float* __restrict__ out)
{
    __shared__ alignas(16) MALDS L;
    const int t=threadIdx.x, w=t>>6, l=t&63, lane16=l&15, lq=l>>4;
    const int idx = blockIdx.x >> 1;

    if ((blockIdx.x & 1) == 0){
        // ---------------- ms part ----------------
        const int b=idx&15, n0=((idx>>4)&7)*64, m0=(idx>>7)*128;
        const int wr=(w>>1)*32, wc=(w&1)*64;

        f4 best[2][4];
        #pragma unroll
        for(int rt=0;rt<2;++rt)
            #pragma unroll
            for(int ct=0;ct<4;++ct)
                #pragma unroll
                for(int i=0;i<4;++i) best[rt][ct][i] = -FLT_MAX;

        for (int h=0;h<4;++h){
            const u16* qh = q + (size_t)(b*4+h)*N_*FO;
            const u16* kh = k + (size_t)(b*4+h)*N_*FO;
            #pragma unroll
            for (int i=0;i<4;++i){
                const int e=t+i*256, row=e>>4, kc=(e&15)*8;
                int n=n0+row; if(n>N_-1)n=N_-1;
                *(bf8*)&L.ms.Qs[row][kc] = ldb8(qh + (size_t)n*FO + kc);
            }
            #pragma unroll
            for (int i=0;i<8;++i){
                const int e=t+i*256, row=e>>4, kc=(e&15)*8;
                int m=m0+row; if(m>N_-1)m=N_-1;
                *(bf8*)&L.ms.Ks[row][kc] = ldb8(kh + (size_t)m*FO + kc);
            }
            __syncthreads();
            f4 acc[2][4]={};
            #pragma unroll
            for (int kk=0;kk<FO;kk+=32){
                bf8 a0=*(const bf8*)&L.ms.Qs[wr+lane16][kk+lq*8];
                bf8 a1=*(const bf8*)&L.ms.Qs[wr+16+lane16][kk+lq*8];
                #pragma unroll
                for(int ct=0;ct<4;++ct){
                    bf8 bb=*(const bf8*)&L.ms.Ks[wc+ct*16+lane16][kk+lq*8];
                    acc[0][ct]=MFMA(a0,bb,acc[0][ct]);
                    acc[1][ct]=MFMA(a1,bb,acc[1][ct]);
                }
            }
            #pragma unroll
            for(int rt=0;rt<2;++rt)
                #pragma unroll
                for(int ct=0;ct<4;++ct)
                    #pragma unroll
                    for(int i=0;i<4;++i) best[rt][ct][i] = fmaxf(best[rt][ct][i], acc[rt][ct][i]);
            __syncthreads();
        }
        #pragma unroll
        for(int rt=0;rt<2;++rt)
            #pragma unroll
            for(int ct=0;ct<4;++ct){
                const int m  = m0+wc+ct*16+lane16;
                const int nb = n0+wr+rt*16+lq*4;
                ushort4 o; o.x=f2b(best[rt][ct][0]); o.y=f2b(best[rt][ct][1]);
                o.z=f2b(best[rt][ct][2]); o.w=f2b(best[rt][ct][3]);
                *(ushort4*)&maxscT[((size_t)b*NP+m)*NP + nb] = o;
            }
    } else {
        // ---------------- attn part ----------------
        const int bh=idx&63, b=bh>>2, h=bh&3, s0=((idx>>6)&3)*32, br=idx>>8;
        const u16* qT = a.qT[br];
        const u16* kp = a.kp[br];
        const u16* vT = a.vT[br];

        { // phase 1: qs partial, k-range [w*128, w*128+128)
            const u16 *ap[2], *bp[4];
            #pragma unroll
            for(int rt=0;rt<2;++rt) ap[rt] = sentB + ((size_t)b*S_ + s0+rt*16+lane16)*NP + w*128 + lq*8;
            #pragma unroll
            for(int ct=0;ct<4;++ct) bp[ct] = qT + ((size_t)bh*FI + ct*16+lane16)*NP + w*128 + lq*8;
            f4 acc[2][4] = {};
            #pragma unroll
            for (int k0=0;k0<128;k0+=32){
                bf8 a0=ldb8(ap[0]+k0), a1=ldb8(ap[1]+k0);
                #pragma unroll
                for(int ct=0;ct<4;++ct){
                    bf8 bb=ldb8(bp[ct]+k0);
                    acc[0][ct]=MFMA(a0,bb,acc[0][ct]);
                    acc[1][ct]=MFMA(a1,bb,acc[1][ct]);
                }
            }
            #pragma unroll
            for(int rt=0;rt<2;++rt)
                #pragma unroll
                for(int ct=0;ct<4;++ct)
                    #pragma unroll
                    for(int reg=0;reg<4;++reg)
                        L.at.red[w][rt*16+lq*4+reg][ct*16+lane16] = acc[rt][ct][reg];
        }
        __syncthreads();
        {
            const int s=t>>3, f0=(t&7)*8;
            #pragma unroll
            for (int j=0;j<8;++j){
                float v = L.at.red[0][s][f0+j]+L.at.red[1][s][f0+j]
                        + L.at.red[2][s][f0+j]+L.at.red[3][s][f0+j];
                L.at.qsS[s][f0+j] = f2b(v);
            }
        }
        __syncthreads();

        f4 accO[2][4] = {};
        #pragma unroll
        for (int c=0;c<2;++c){
            const int m0 = w*64 + c*256;
            f4 p[2][4] = {};
            const u16* bp[4];
            #pragma unroll
            for(int ct=0;ct<4;++ct){
                int m=m0+ct*16+lane16; if(m>N_-1)m=N_-1;
                bp[ct] = kp + ((size_t)bh*N_+m)*FI + lq*8;
            }
            #pragma unroll
            for (int kk=0; kk<FI; kk+=32){
                bf8 a0 = *(const bf8*)&L.at.qsS[lane16][kk+lq*8];
                bf8 a1 = *(const bf8*)&L.at.qsS[16+lane16][kk+lq*8];
                #pragma unroll
                for(int ct=0;ct<4;++ct){
                    bf8 bb=ldb8(bp[ct]+kk);
                    p[0][ct]=MFMA(a0,bb,p[0][ct]);
                    p[1][ct]=MFMA(a1,bb,p[1][ct]);
                }
            }
            #pragma unroll
            for(int rt=0;rt<2;++rt)
                #pragma unroll
                for(int ct=0;ct<4;++ct){
                    const int m = m0+ct*16+lane16;
                    #pragma unroll
                    for(int reg=0;reg<4;++reg){
                        const int s = s0+rt*16+lq*4+reg;
                        const float sv = b2f(sentB[((size_t)b*S_+s)*NP+m]);
                        const float wgt = br ? ((m<N_)? sv-1.f : 0.f) : sv;
                        L.at.Pw[w][rt*16+lq*4+reg][ct*16+lane16] = f2b(p[rt][ct][reg]*wgt);
                    }
                }
            #pragma unroll
            for (int kk2=0; kk2<64; kk2+=32){
                bf8 a2[2];
                #pragma unroll
                for(int rt=0;rt<2;++rt) a2[rt] = *(const bf8*)&L.at.Pw[w][rt*16+lane16][kk2+lq*8];
                #pragma unroll
                for(int ct=0;ct<4;++ct){
                    bf8 vv = ldb8(vT + ((size_t)bh*FI + ct*16+lane16)*NP + m0+kk2+lq*8);
                    accO[0][ct]=MFMA(a2[0],vv,accO[0][ct]);
                    accO[1][ct]=MFMA(a2[1],vv,accO[1][ct]);
                }
            }
        }
        #pragma unroll
        for(int rt=0;rt<2;++rt)
            #pragma unroll
            for(int ct=0;ct<4;++ct)
                #pragma unroll
                for(int reg=0;reg<4;++reg)
                    L.at.red[w][rt*16+lq*4+reg][ct*16+lane16] = accO[rt][ct][reg];
        __syncthreads();
        {
            const int s=t>>3, f0=(t&7)*8;
            float fac = 1.f;
            if (br){ const float ic = inc[b*S_+s0+s]; fac = ic/(500.f-ic); }
            const size_t o = ((size_t)b*S_+s0+s)*1024 + (br?768:512) + h*FI + f0;
            #pragma unroll
            for (int j=0;j<8;++j){
                float v = L.at.red[0][s][f0+j]+L.at.red[1][s][f0+j]
                        + L.at.red[2][s][f0+j]+L.at.red[3][s][f0+j];
                out[o+j] = v*fac;
            }
        }
    }
}

// =====================================================================
// saoo: fused  sAm = sent ⊙ (sent @ maxscT)  then  out_ori = sAm @ code
// grid (16 b, 8 stile16), block 512 (8 waves).
// =====================================================================
__global__ __launch_bounds__(512) void saoo(const u16* __restrict__ sentB,
                                            const u16* __restrict__ maxscT,
                                            const u16* __restrict__ codeT,
                                            float* __restrict__ out)
{
    __shared__ u16 sAmS[16][520];
    const int b=blockIdx.x, s0=blockIdx.y*16;
    const int t=threadIdx.x, w=t>>6, l=t&63, lane16=l&15, lq=l>>4;

    { // phase 1: m-chunk w
        const int m0 = w*64;
        const u16* ap = sentB + ((size_t)b*S_ + s0+lane16)*NP + lq*8;
        const u16* bp[4];
        #pragma unroll
        for(int ct=0;ct<4;++ct) bp[ct] = maxscT + ((size_t)b*NP + m0+ct*16+lane16)*NP + lq*8;
        f4 acc[4] = {};
        for (int k0=0;k0<NP;k0+=32){
            bf8 av=ldb8(ap+k0);
            #pragma unroll
            for(int ct=0;ct<4;++ct) acc[ct]=MFMA(av, ldb8(bp[ct]+k0), acc[ct]);
        }
        #pragma unroll
        for(int ct=0;ct<4;++ct){
            const int m = m0+ct*16+lane16;
            #pragma unroll
            for(int reg=0;reg<4;++reg){
                const int s = s0+lq*4+reg;
                const float sv = b2f(sentB[((size_t)b*S_+s)*NP+m]);
                sAmS[lq*4+reg][m] = (sv != 0.f) ? f2b(acc[ct][reg]*sv) : (u16)0;
            }
        }
    }
    __syncthreads();
    { // phase 2: d-chunk w
        const int d0 = w*64;
        const u16* bp[4];
        #pragma unroll
        for(int ct=0;ct<4;++ct) bp[ct] = codeT + ((size_t)b*D_ + d0+ct*16+lane16)*NP + lq*8;
        f4 acc[4] = {};
        for (int k0=0;k0<NP;k0+=32){
            bf8 av = *(const bf8*)&sAmS[lane16][k0+lq*8];
            #pragma unroll
            for(int ct=0;ct<4;++ct) acc[ct]=MFMA(av, ldb8(bp[ct]+k0), acc[ct]);
        }
        #pragma unroll
        for(int ct=0;ct<4;++ct){
            const int d = d0+ct*16+lane16;
            #pragma unroll
            for(int reg=0;reg<4;++reg){
                const int s = s0+lq*4+reg;
                out[((size_t)b*S_+s)*1024 + d] = acc[ct][reg];
            }
        }
    }
}

// =====================================================================
extern "C" void kernel_launch(void* const* d_in, const int* in_sizes, int n_in,
                              void* d_out, int out_size, void* d_ws, size_t ws_size,
                              hipStream_t stream)
{
    const float* code   = (const float*)d_in[0];
    const float* sent   = (const float*)d_in[1];
    const float* Wq_ori = (const float*)d_in[2];
    const float* bq_ori = (const float*)d_in[3];
    const float* Wk_ori = (const float*)d_in[4];
    const float* bk_ori = (const float*)d_in[5];
    const float* Wq_in  = (const float*)d_in[6];
    const float* bq_in  = (const float*)d_in[7];
    const float* Wk_in  = (const float*)d_in[8];
    const float* bk_in  = (const float*)d_in[9];
    const float* Wv_in  = (const float*)d_in[10];
    const float* bv_in  = (const float*)d_in[11];
    const float* Wq_out = (const float*)d_in[12];
    const float* bq_out = (const float*)d_in[13];
    const float* Wk_out = (const float*)d_in[14];
    const float* bk_out = (const float*)d_in[15];
    const float* Wv_out = (const float*)d_in[16];
    const float* bv_out = (const float*)d_in[17];
    float* out = (float*)d_out;

    // fully disjoint workspace (~71 MB; ws is ~268 MB)
    char* w = (char*)d_ws;
    u16*   codeB  = (u16*)(w);                  // 8192*512*2 = 8,388,608 B
    u16*   WallT  = (u16*)(w + 8388608);        // 2560*512*2 = 2,621,440 B
    u16*   WTqo   = WallT;
    u16*   WTko   = WallT +  262144;
    u16*   WTqi   = WallT +  524288;
    u16*   WTki   = WallT +  655360;
    u16*   WTvi   = WallT +  786432;
    u16*   WTqu   = WallT +  917504;
    u16*   WTku   = WallT + 1048576;
    u16*   WTvu   = WallT + 1179648;
    u16*   sentB  = (u16*)(w + 11010048);       // 2,097,152
    float* incp   = (float*)(w + 13107200);     // 8,192
    u16* q_ori  = (u16*)(w + 13115392);         // 8,192,000
    u16* k_ori  = (u16*)(w + 21307392);         // 8,192,000
    u16* maxscT = (u16*)(w + 29499392);         // 8,388,608
    u16* codeT  = (u16*)(w + 37888000);         // 8,388,608
    u16* k_in   = (u16*)(w + 46276608);         // 4,096,000
    u16* k_out  = (u16*)(w + 50372608);         // 4,096,000
    u16* qT_in  = (u16*)(w + 54468608);         // 4,194,304
    u16* qT_out = (u16*)(w + 58662912);
    u16* vT_in  = (u16*)(w + 62857216);
    u16* vT_out = (u16*)(w + 67051520);         // ends 71,245,824

    // ---- prep (1 launch) ----
    PWAll pw;
    pw.W[0]=Wq_ori; pw.W[1]=Wk_ori; pw.W[2]=Wq_in; pw.W[3]=Wk_in;
    pw.W[4]=Wv_in;  pw.W[5]=Wq_out; pw.W[6]=Wk_out; pw.W[7]=Wv_out;
    pw.WT[0]=WTqo; pw.WT[1]=WTko; pw.WT[2]=WTqi; pw.WT[3]=WTki;
    pw.WT[4]=WTvi; pw.WT[5]=WTqu; pw.WT[6]=WTku; pw.WT[7]=WTvu;
    prep_fused<<<dim3(2624), 256, 0, stream>>>(code, codeB, codeT, pw,
                                               sent, sentB, incp,
                                               qT_in, qT_out, vT_in, vT_out);

    // ---- single projection GEMM for all 20 col-tiles ----
    GemmOut go;
    go.bias[0]=bq_ori; go.bias[1]=bk_ori; go.bias[2]=bq_in; go.bias[3]=bk_in;
    go.bias[4]=bv_in;  go.bias[5]=bq_out; go.bias[6]=bk_out; go.bias[7]=bv_out;
    go.dst[0]=q_ori; go.dst[1]=k_ori; go.dst[2]=qT_in; go.dst[3]=k_in;
    go.dst[4]=vT_in; go.dst[5]=qT_out; go.dst[6]=k_out; go.dst[7]=vT_out;
    proj_gemm<<<dim3(1280), 256, 0, stream>>>(codeB, WallT, go);

    // ---- ms + attn fused (independent work, co-scheduled) ----
    AttnArgs aa;
    aa.qT[0]=qT_in;  aa.qT[1]=qT_out;
    aa.kp[0]=k_in;   aa.kp[1]=k_out;
    aa.vT[0]=vT_in;  aa.vT[1]=vT_out;
    msattn<<<dim3(1024), 256, 0, stream>>>(q_ori, k_ori, maxscT, aa, sentB, incp, out);

    // ---- ori epilogue ----
    saoo<<<dim3(16,8), 512, 0, stream>>>(sentB, maxscT, codeT, out);
}